// Round 4
// baseline (29.974 us; speedup 1.0000x reference)
//
#include <hip/hip_runtime.h>
#include <math.h>

#define BB 2048   // batch B
#define NN 512    // classes N
#define DD 256    // dim D

typedef __attribute__((ext_vector_type(8))) short s16x8;   // 8 bf16
typedef __attribute__((ext_vector_type(4))) float f32x4;

#define MFMA_BF16 __builtin_amdgcn_mfma_f32_16x16x32_bf16

__device__ __forceinline__ ushort f2bf(float f) {          // RNE f32->bf16
    union { float f; unsigned u; } c; c.f = f;
    return (ushort)((c.u + 0x7fffu + ((c.u >> 16) & 1u)) >> 16);
}
__device__ __forceinline__ float bf2f(ushort h) {
    union { unsigned u; float f; } c; c.u = ((unsigned)h) << 16;
    return c.f;
}

// scale 4 floats, split each into bf16 hi + bf16 lo (RNE both), pack pairs
__device__ __forceinline__ void split4(f32x4 v, float s, uint2* hi, uint2* lo) {
    float a = v.x * s, b = v.y * s, c = v.z * s, d = v.w * s;
    ushort ha = f2bf(a), hb = f2bf(b), hc = f2bf(c), hd = f2bf(d);
    ushort la = f2bf(a - bf2f(ha)), lb = f2bf(b - bf2f(hb));
    ushort lc = f2bf(c - bf2f(hc)), ld = f2bf(d - bf2f(hd));
    hi->x = (unsigned)ha | ((unsigned)hb << 16);
    hi->y = (unsigned)hc | ((unsigned)hd << 16);
    lo->x = (unsigned)la | ((unsigned)lb << 16);
    lo->y = (unsigned)lc | ((unsigned)ld << 16);
}

// Fused kernel: block = 64 b-rows x 32 n-cols. Phases:
// reg-stage fp32 -> shfl row-sums -> per-row scalars -> two K=128 rounds of
// {scale+split+swizzled LDS write, dual compensated MFMA GEMM} -> asinh epilogue.
__global__ __launch_bounds__(256, 2) void hmlr_fused(
    const float* __restrict__ x, const float* __restrict__ a_vals,
    const float* __restrict__ p_vals, float* __restrict__ out)
{
    __shared__ ushort Xh[64][128], Xl[64][128];                  // 32 KiB
    __shared__ ushort Ph[32][128], Pl[32][128];                  // 16 KiB
    __shared__ ushort Ah[32][128], Al[32][128];                  // 16 KiB
    __shared__ float xs2[64], pn2[32], an2[32], pan[32];
    __shared__ float sXs[64], y2s[64], sPs[32], cfs[32];
    __shared__ float p2sl[32], pasl[32], ansl[32], ksl[32];

    const int t    = threadIdx.x;
    const int lane = t & 63;
    const int w    = t >> 6;          // wave 0..3
    const int wr   = w >> 1;          // b-half (32 rows)
    const int wc   = w & 1;           // n-half (16 cols)
    const int n0   = blockIdx.x * 32;
    const int b0   = blockIdx.y * 64;
    const int kcol = lane * 4;        // this lane's 4 k-elements

    // ---- stage all operand rows into registers (raw fp32) ----
    f32x4 xg[16], pg[8], ag[8];
    #pragma unroll
    for (int i = 0; i < 16; ++i)
        xg[i] = *(const f32x4*)&x[(size_t)(b0 + w * 16 + i) * DD + kcol];
    #pragma unroll
    for (int i = 0; i < 8; ++i) {
        pg[i] = *(const f32x4*)&p_vals[(size_t)(n0 + w * 8 + i) * DD + kcol];
        ag[i] = *(const f32x4*)&a_vals[(size_t)(n0 + w * 8 + i) * DD + kcol];
    }

    // ---- row sums via 64-lane butterfly ----
    #pragma unroll
    for (int i = 0; i < 16; ++i) {
        f32x4 v = xg[i];
        float ss = v.x * v.x + v.y * v.y + v.z * v.z + v.w * v.w;
        #pragma unroll
        for (int m = 32; m; m >>= 1) ss += __shfl_xor(ss, m, 64);
        if (lane == 0) xs2[w * 16 + i] = ss;
    }
    #pragma unroll
    for (int i = 0; i < 8; ++i) {
        f32x4 pv = pg[i], av = ag[i];
        float sp = pv.x * pv.x + pv.y * pv.y + pv.z * pv.z + pv.w * pv.w;
        float sa = av.x * av.x + av.y * av.y + av.z * av.z + av.w * av.w;
        float sx = pv.x * av.x + pv.y * av.y + pv.z * av.z + pv.w * av.w;
        #pragma unroll
        for (int m = 32; m; m >>= 1) {
            sp += __shfl_xor(sp, m, 64);
            sa += __shfl_xor(sa, m, 64);
            sx += __shfl_xor(sx, m, 64);
        }
        if (lane == 0) { pn2[w * 8 + i] = sp; an2[w * 8 + i] = sa; pan[w * 8 + i] = sx; }
    }
    __syncthreads();

    // ---- per-row scalars ----
    if (t < 64) {
        float norm0 = sqrtf(xs2[t]);
        float fac = fminf(1.0f, 1.0f / (norm0 + 1e-5f));      // CLIP_R = 1
        float u = fmaxf(norm0 * fac, 1e-5f);
        float th = tanhf(u);                                   // sqrt_c = 1
        float en = fmaxf(th, 1e-5f);
        float wgt = (en > 0.999f) ? (0.999f / en) : 1.0f;      // project
        sXs[t] = fac * (th / u) * wgt;                         // x -> xb scale
        float fn = th * wgt;
        y2s[t] = fn * fn;
    } else if (t < 96) {
        int j = t - 64;
        float u = fmaxf(sqrtf(pn2[j]), 1e-5f);
        float th = tanhf(u);
        float sp = th / u;                                     // p -> p_poincare
        float p2 = th * th;
        float conf = 1.0f - p2;                                // conformal
        sPs[j] = sp; cfs[j] = conf; p2sl[j] = p2;
        pasl[j] = sp * conf * pan[j];                          // P . A
        float an = sqrtf(an2[j]) * conf;                       // ||a_poincare||
        ansl[j] = an;
        ksl[j] = (2.0f / conf) * an;                           // lam * a_norm
    }
    __syncthreads();

    // ---- dual compensated GEMM over two K=128 halves ----
    f32x4 axy0 = {0.f,0.f,0.f,0.f}, axy1 = {0.f,0.f,0.f,0.f};
    f32x4 axa0 = {0.f,0.f,0.f,0.f}, axa1 = {0.f,0.f,0.f,0.f};
    const int half = lane >> 5;          // which k-half this lane holds
    const int kk8  = (lane & 31) * 8;    // byte offset within a 256B LDS row
    const int ra0  = wr * 32 + (lane & 15);
    const int ra1  = ra0 + 16;
    const int rbn  = wc * 16 + (lane & 15);
    const int gb   = (lane >> 4) << 4;   // frag 16B-group byte offset

    for (int h = 0; h < 2; ++h) {
        if (half == h) {                 // fill swizzled LDS tiles
            #pragma unroll
            for (int i = 0; i < 16; ++i) {
                int r = w * 16 + i;
                int byt = kk8 ^ ((r & 7) << 4);
                uint2 hi, lo;
                split4(xg[i], sXs[r], &hi, &lo);
                *(uint2*)((char*)&Xh[r][0] + byt) = hi;
                *(uint2*)((char*)&Xl[r][0] + byt) = lo;
            }
            #pragma unroll
            for (int i = 0; i < 8; ++i) {
                int r = w * 8 + i;
                int byt = kk8 ^ ((r & 7) << 4);
                uint2 hi, lo;
                split4(pg[i], sPs[r], &hi, &lo);
                *(uint2*)((char*)&Ph[r][0] + byt) = hi;
                *(uint2*)((char*)&Pl[r][0] + byt) = lo;
                split4(ag[i], cfs[r], &hi, &lo);
                *(uint2*)((char*)&Ah[r][0] + byt) = hi;
                *(uint2*)((char*)&Al[r][0] + byt) = lo;
            }
        }
        __syncthreads();
        #pragma unroll
        for (int ks = 0; ks < 4; ++ks) {
            const int kb = ks * 64 + gb;
            const int sa = kb ^ ((ra0 & 7) << 4);
            const int sb = kb ^ ((rbn & 7) << 4);
            s16x8 xh0v = *(const s16x8*)((const char*)&Xh[ra0][0] + sa);
            s16x8 xl0v = *(const s16x8*)((const char*)&Xl[ra0][0] + sa);
            s16x8 xh1v = *(const s16x8*)((const char*)&Xh[ra1][0] + sa);
            s16x8 xl1v = *(const s16x8*)((const char*)&Xl[ra1][0] + sa);
            s16x8 phv  = *(const s16x8*)((const char*)&Ph[rbn][0] + sb);
            s16x8 plv  = *(const s16x8*)((const char*)&Pl[rbn][0] + sb);
            s16x8 ahv  = *(const s16x8*)((const char*)&Ah[rbn][0] + sb);
            s16x8 alv  = *(const s16x8*)((const char*)&Al[rbn][0] + sb);
            axy0 = MFMA_BF16(xh0v, phv, axy0, 0, 0, 0);
            axy0 = MFMA_BF16(xh0v, plv, axy0, 0, 0, 0);
            axy0 = MFMA_BF16(xl0v, phv, axy0, 0, 0, 0);
            axy1 = MFMA_BF16(xh1v, phv, axy1, 0, 0, 0);
            axy1 = MFMA_BF16(xh1v, plv, axy1, 0, 0, 0);
            axy1 = MFMA_BF16(xl1v, phv, axy1, 0, 0, 0);
            axa0 = MFMA_BF16(xh0v, ahv, axa0, 0, 0, 0);
            axa0 = MFMA_BF16(xh0v, alv, axa0, 0, 0, 0);
            axa0 = MFMA_BF16(xl0v, ahv, axa0, 0, 0, 0);
            axa1 = MFMA_BF16(xh1v, ahv, axa1, 0, 0, 0);
            axa1 = MFMA_BF16(xh1v, alv, axa1, 0, 0, 0);
            axa1 = MFMA_BF16(xl1v, ahv, axa1, 0, 0, 0);
        }
        __syncthreads();
    }

    // ---- epilogue: C/D map col=lane&15, row=(lane>>4)*4+reg ----
    const int nl = rbn;                  // wc*16 + (lane&15)
    const float p2 = p2sl[nl], pa = pasl[nl], an = ansl[nl], kk = ksl[nl];
    const int n = n0 + nl;
    #pragma unroll
    for (int m = 0; m < 2; ++m) {
        f32x4 acc_xy = m ? axy1 : axy0;
        f32x4 acc_xa = m ? axa1 : axa0;
        #pragma unroll
        for (int rg = 0; rg < 4; ++rg) {
            int bl = wr * 32 + m * 16 + (lane >> 4) * 4 + rg;
            float yy  = y2s[bl];
            float xy  = -acc_xy[rg];                     // (-P).X
            float xa  =  acc_xa[rg];
            float dnm = 1.f + 2.f * xy + p2 * yy + 1e-5f;
            float alpha = (1.f + 2.f * xy + yy) / dnm;   // coeff on (-P)
            float beta  = (1.f - p2) / dnm;              // coeff on X
            float num  = 2.f * (beta * xa - alpha * pa);
            float mob2 = alpha * alpha * p2 + beta * beta * yy
                       + 2.f * alpha * beta * xy;
            float den  = an * (1.f - mob2);
            out[(size_t)(b0 + bl) * NN + n] = kk * asinhf(num / den);
        }
    }
}

extern "C" void kernel_launch(void* const* d_in, const int* in_sizes, int n_in,
                              void* d_out, int out_size, void* d_ws, size_t ws_size,
                              hipStream_t stream) {
    const float* x      = (const float*)d_in[0];
    const float* a_vals = (const float*)d_in[1];
    const float* p_vals = (const float*)d_in[2];
    float* out = (float*)d_out;

    hipLaunchKernelGGL(hmlr_fused, dim3(NN / 32, BB / 64), dim3(256), 0, stream,
                       x, a_vals, p_vals, out);
}

// Round 5
// 22.132 us; speedup vs baseline: 1.3543x; 1.3543x over previous
//
#include <hip/hip_runtime.h>
#include <math.h>

#define BB 2048   // batch B
#define NN 512    // classes N
#define DD 256    // dim D

typedef __attribute__((ext_vector_type(8))) short s16x8;   // 8 bf16
typedef __attribute__((ext_vector_type(4))) float f32x4;

#define MFMA_BF16 __builtin_amdgcn_mfma_f32_16x16x32_bf16

__device__ __forceinline__ ushort f2bf(float f) {          // RNE f32->bf16
    union { float f; unsigned u; } c; c.f = f;
    return (ushort)((c.u + 0x7fffu + ((c.u >> 16) & 1u)) >> 16);
}
__device__ __forceinline__ float bf2f(ushort h) {
    union { unsigned u; float f; } c; c.u = ((unsigned)h) << 16;
    return c.f;
}

// scale 4 floats, split each into bf16 hi + bf16 lo (RNE both), pack pairs
__device__ __forceinline__ void split4(f32x4 v, float s, uint2* hi, uint2* lo) {
    float a = v.x * s, b = v.y * s, c = v.z * s, d = v.w * s;
    ushort ha = f2bf(a), hb = f2bf(b), hc = f2bf(c), hd = f2bf(d);
    ushort la = f2bf(a - bf2f(ha)), lb = f2bf(b - bf2f(hb));
    ushort lc = f2bf(c - bf2f(hc)), ld = f2bf(d - bf2f(hd));
    hi->x = (unsigned)ha | ((unsigned)hb << 16);
    hi->y = (unsigned)hc | ((unsigned)hd << 16);
    lo->x = (unsigned)la | ((unsigned)lb << 16);
    lo->y = (unsigned)lc | ((unsigned)ld << 16);
}

// ---------------- Stage 1: one WAVE per row, no barriers ----------------
// Rows [0,BB): x -> Poincare ball, write bf16 hi/lo pre-swizzled.
// Rows [BB,BB+NN): p,a -> p_poincare / a_poincare + per-row scalars.
// Pre-swizzle: within each 64-elem k-chunk, el ^= (row&7)<<3  (involution,
// matches stage2's ds_read XOR on byte bits 4..6).
__global__ __launch_bounds__(256) void hmlr_transform(
    const float* __restrict__ x, const float* __restrict__ a_vals,
    const float* __restrict__ p_vals,
    ushort* __restrict__ Xh, ushort* __restrict__ Xl,
    ushort* __restrict__ Ph, ushort* __restrict__ Pl,
    ushort* __restrict__ Ah, ushort* __restrict__ Al,
    float* __restrict__ y2, float* __restrict__ p2s, float* __restrict__ pas,
    float* __restrict__ ans, float* __restrict__ ks)
{
    const int lane = threadIdx.x & 63;
    const int wid  = blockIdx.x * 4 + (threadIdx.x >> 6);   // row id, < BB+NN
    const int e0   = lane * 4;                              // 4 elems per lane

    if (wid < BB) {
        const int r = wid;
        f32x4 v = *(const f32x4*)&x[(size_t)r * DD + e0];
        float ss = v.x * v.x + v.y * v.y + v.z * v.z + v.w * v.w;
        #pragma unroll
        for (int m = 32; m; m >>= 1) ss += __shfl_xor(ss, m, 64);
        float norm0 = sqrtf(ss);
        float fac = fminf(1.0f, 1.0f / (norm0 + 1e-5f));    // CLIP_R = 1
        float u = fmaxf(norm0 * fac, 1e-5f);
        float th = tanhf(u);                                 // sqrt_c = 1
        float en = fmaxf(th, 1e-5f);
        float wgt = (en > 0.999f) ? (0.999f / en) : 1.0f;    // project
        float s = fac * (th / u) * wgt;                      // x -> xb scale
        if (lane == 0) { float fn = th * wgt; y2[r] = fn * fn; }
        uint2 hi, lo;
        split4(v, s, &hi, &lo);
        int es = e0 ^ ((r & 7) << 3);
        *(uint2*)&Xh[(size_t)r * DD + es] = hi;
        *(uint2*)&Xl[(size_t)r * DD + es] = lo;
    } else {
        const int n = wid - BB;
        f32x4 pv = *(const f32x4*)&p_vals[(size_t)n * DD + e0];
        f32x4 av = *(const f32x4*)&a_vals[(size_t)n * DD + e0];
        float sp = pv.x * pv.x + pv.y * pv.y + pv.z * pv.z + pv.w * pv.w;
        float sa = av.x * av.x + av.y * av.y + av.z * av.z + av.w * av.w;
        float sx = pv.x * av.x + pv.y * av.y + pv.z * av.z + pv.w * av.w;
        #pragma unroll
        for (int m = 32; m; m >>= 1) {
            sp += __shfl_xor(sp, m, 64);
            sa += __shfl_xor(sa, m, 64);
            sx += __shfl_xor(sx, m, 64);
        }
        float u = fmaxf(sqrtf(sp), 1e-5f);
        float th = tanhf(u);
        float spp = th / u;                                  // p -> p_poincare
        float p2 = th * th;
        float conf = 1.0f - p2;                              // conformal
        if (lane == 0) {
            p2s[n] = p2;
            pas[n] = spp * conf * sx;                        // P . A
            float an = sqrtf(sa) * conf;                     // ||a_poincare||
            ans[n] = an;
            ks[n] = (2.0f / conf) * an;                      // lam * a_norm
        }
        int es = e0 ^ ((n & 7) << 3);
        uint2 hi, lo;
        split4(pv, spp, &hi, &lo);
        *(uint2*)&Ph[(size_t)n * DD + es] = hi;
        *(uint2*)&Pl[(size_t)n * DD + es] = lo;
        split4(av, conf, &hi, &lo);
        *(uint2*)&Ah[(size_t)n * DD + es] = hi;
        *(uint2*)&Al[(size_t)n * DD + es] = lo;
    }
}

// ---------------- Stage 2: 64x64 tile, 8 waves, BK=64 dbuf ----------------
// Dynamic LDS: [2][6][64][64] ushort = 96 KiB. Mats: Xh,Xl,Ph,Pl,Ah,Al.
// global_load_lds width-16 from pre-swizzled arrays (linear dest);
// ds_read applies byte ^ ((row&7)<<4). Dual compensated GEMM + asinh epilogue.
__global__ __launch_bounds__(512) void hmlr_gemm(
    const ushort* __restrict__ Xh, const ushort* __restrict__ Xl,
    const ushort* __restrict__ Ph, const ushort* __restrict__ Pl,
    const ushort* __restrict__ Ah, const ushort* __restrict__ Al,
    const float* __restrict__ y2, const float* __restrict__ p2s,
    const float* __restrict__ pas, const float* __restrict__ ans,
    const float* __restrict__ ks, float* __restrict__ out)
{
    extern __shared__ ushort T[];          // [2][6][64][64]

    const int t    = threadIdx.x;
    const int lane = t & 63;
    const int w    = t >> 6;               // wave 0..7
    const int wr   = w >> 2;               // m half: 32 rows
    const int wc   = w & 3;                // n strip: 16 cols
    const int n0   = blockIdx.x * 64;
    const int b0   = blockIdx.y * 64;

    const ushort* bases[6] = {Xh, Xl, Ph, Pl, Ah, Al};

    f32x4 axy0 = {0.f,0.f,0.f,0.f}, axy1 = {0.f,0.f,0.f,0.f};
    f32x4 axa0 = {0.f,0.f,0.f,0.f}, axa1 = {0.f,0.f,0.f,0.f};

    // Stage one BK=64 slice of all 6 mats (48 KiB) into buf. 48 wave-chunks:
    // g = w*6+i; mat = g>>3; 8-row group sub = g&7. Each instr moves 1 KiB.
    auto stage = [&](int buf, int s) {
        #pragma unroll
        for (int i = 0; i < 6; ++i) {
            int g = w * 6 + i;
            int mat = g >> 3;
            int sub = g & 7;
            int grow = (mat < 2 ? b0 : n0) + sub * 8 + (lane >> 3);
            const ushort* src = bases[mat] + (size_t)grow * DD + s * 64 + (lane & 7) * 8;
            const ushort* dst = T + (((buf * 6 + mat) * 64 + sub * 8) * 64);
            __builtin_amdgcn_global_load_lds(
                (const __attribute__((address_space(1))) unsigned int*)(const void*)src,
                (__attribute__((address_space(3))) unsigned int*)(void*)dst,
                16, 0, 0);
        }
    };

    const int ram = wr * 32 + (lane & 15);
    const int rbn = wc * 16 + (lane & 15);
    const int gb  = (lane >> 4) << 4;      // 16B group within 64B half-row

    stage(0, 0);
    for (int s = 0; s < 4; ++s) {
        __syncthreads();                   // vmcnt drain: buf[s&1] ready
        if (s < 3) stage((s + 1) & 1, s + 1);
        const int bf = s & 1;
        #pragma unroll
        for (int ksl = 0; ksl < 2; ++ksl) {
            const int kb = ksl * 64 + gb;
            const ushort* base = T + (bf * 6 * 64 * 64);
            const char* x0 = (const char*)(base + (0 * 64 + ram) * 64);
            const char* x1 = (const char*)(base + (1 * 64 + ram) * 64);
            const int sa0 = kb ^ ((ram & 7) << 4);
            const int sb0 = kb ^ ((rbn & 7) << 4);
            const int sa1 = kb ^ (((ram + 16) & 7) << 4);   // == sa0 (16 | 7)
            s16x8 xh0 = *(const s16x8*)(x0 + sa0);
            s16x8 xh1 = *(const s16x8*)(x0 + 16 * 128 + sa1);
            s16x8 xl0 = *(const s16x8*)(x1 + sa0);
            s16x8 xl1 = *(const s16x8*)(x1 + 16 * 128 + sa1);
            s16x8 ph  = *(const s16x8*)((const char*)(base + (2 * 64 + rbn) * 64) + sb0);
            s16x8 pl  = *(const s16x8*)((const char*)(base + (3 * 64 + rbn) * 64) + sb0);
            s16x8 ah  = *(const s16x8*)((const char*)(base + (4 * 64 + rbn) * 64) + sb0);
            s16x8 al  = *(const s16x8*)((const char*)(base + (5 * 64 + rbn) * 64) + sb0);
            axy0 = MFMA_BF16(xh0, ph, axy0, 0, 0, 0);
            axy0 = MFMA_BF16(xh0, pl, axy0, 0, 0, 0);
            axy0 = MFMA_BF16(xl0, ph, axy0, 0, 0, 0);
            axy1 = MFMA_BF16(xh1, ph, axy1, 0, 0, 0);
            axy1 = MFMA_BF16(xh1, pl, axy1, 0, 0, 0);
            axy1 = MFMA_BF16(xl1, ph, axy1, 0, 0, 0);
            axa0 = MFMA_BF16(xh0, ah, axa0, 0, 0, 0);
            axa0 = MFMA_BF16(xh0, al, axa0, 0, 0, 0);
            axa0 = MFMA_BF16(xl0, ah, axa0, 0, 0, 0);
            axa1 = MFMA_BF16(xh1, ah, axa1, 0, 0, 0);
            axa1 = MFMA_BF16(xh1, al, axa1, 0, 0, 0);
            axa1 = MFMA_BF16(xl1, ah, axa1, 0, 0, 0);
        }
    }

    // Epilogue. C/D map: col = lane&15, row = (lane>>4)*4 + reg.
    const int n = n0 + rbn;
    const float p2 = p2s[n], pa = pas[n], an = ans[n], kk = ks[n];
    #pragma unroll
    for (int m = 0; m < 2; ++m) {
        f32x4 acc_xy = m ? axy1 : axy0;
        f32x4 acc_xa = m ? axa1 : axa0;
        #pragma unroll
        for (int rg = 0; rg < 4; ++rg) {
            int b = b0 + wr * 32 + m * 16 + (lane >> 4) * 4 + rg;
            float yy  = y2[b];
            float xy  = -acc_xy[rg];                     // (-P).X
            float xa  =  acc_xa[rg];
            float dnm = 1.f + 2.f * xy + p2 * yy + 1e-5f;
            float alpha = (1.f + 2.f * xy + yy) / dnm;   // coeff on (-P)
            float beta  = (1.f - p2) / dnm;              // coeff on X
            float num  = 2.f * (beta * xa - alpha * pa);
            float mob2 = alpha * alpha * p2 + beta * beta * yy
                       + 2.f * alpha * beta * xy;
            float den  = an * (1.f - mob2);
            out[(size_t)b * NN + n] = kk * asinhf(num / den);
        }
    }
}

extern "C" void kernel_launch(void* const* d_in, const int* in_sizes, int n_in,
                              void* d_out, int out_size, void* d_ws, size_t ws_size,
                              hipStream_t stream) {
    const float* x      = (const float*)d_in[0];
    const float* a_vals = (const float*)d_in[1];
    const float* p_vals = (const float*)d_in[2];
    float* out = (float*)d_out;

    ushort* Xh = (ushort*)d_ws;                 // [BB][DD] bf16 hi (pre-swizzled)
    ushort* Xl = Xh + (size_t)BB * DD;
    ushort* Ph = Xl + (size_t)BB * DD;          // [NN][DD]
    ushort* Pl = Ph + (size_t)NN * DD;
    ushort* Ah = Pl + (size_t)NN * DD;
    ushort* Al = Ah + (size_t)NN * DD;
    float*  y2  = (float*)(Al + (size_t)NN * DD);
    float*  p2s = y2 + BB;
    float*  pas = p2s + NN;
    float*  ans = pas + NN;
    float*  ks  = ans + NN;

    static bool attr_set = false;
    (void)hipFuncSetAttribute(reinterpret_cast<const void*>(hmlr_gemm),
                              hipFuncAttributeMaxDynamicSharedMemorySize, 98304);

    hipLaunchKernelGGL(hmlr_transform, dim3((BB + NN) / 4), dim3(256), 0, stream,
                       x, a_vals, p_vals, Xh, Xl, Ph, Pl, Ah, Al,
                       y2, p2s, pas, ans, ks);
    hipLaunchKernelGGL(hmlr_gemm, dim3(NN / 64, BB / 64), dim3(512), 98304, stream,
                       Xh, Xl, Ph, Pl, Ah, Al, y2, p2s, pas, ans, ks, out);
}